// Round 13
// baseline (28.225 us; speedup 1.0000x reference)
//
#include <hip/hip_runtime.h>

#define DIM   128
#define PLANE (DIM*DIM)
#define TD    8

typedef float vfloat4 __attribute__((ext_vector_type(4)));

__global__ __launch_bounds__(256, 4) void conv3d_circ_st(
    const float* __restrict__ x, const float* __restrict__ kern,
    float* __restrict__ out)
{
    const int tid = threadIdx.x;
    const int bid = blockIdx.x;
    const int b  = bid >> 7;          // 8 batches (8 ht x 16 dt = 128 blocks/batch)
    const int ht = (bid >> 4) & 7;    // 8 h-tiles of 16 rows
    const int dt = bid & 15;          // 16 d-chunks of 8 planes
    const int h0 = ht * 16;
    const int d0 = dt * TD;

    const int wq   = (tid & 31) * 4;        // 4 outputs along w; 32 lanes = full W
    const int hg   = h0 + (tid >> 5) * 2;   // this thread's 2 h rows: hg, hg+1
    const int lane = tid & 63;
    const int lleft  = (lane & 32) | ((lane - 1) & 31);  // wrap within 32-lane w-ring
    const int lright = (lane & 32) | ((lane + 1) & 31);

    // 4 tap rows: hg-1, hg, hg+1, hg+2 (wrapped)
    const int ro[4] = {((hg - 1) & (DIM - 1)) * DIM + wq,
                       hg * DIM + wq,
                       ((hg + 1) & (DIM - 1)) * DIM + wq,
                       ((hg + 2) & (DIM - 1)) * DIM + wq};

    float K0[9], K1[9], K2[9];        // uniform -> scalar loads -> SGPRs
#pragma unroll
    for (int i = 0; i < 9; ++i) { K0[i] = kern[i]; K1[i] = kern[9 + i]; K2[i] = kern[18 + i]; }

    const float* xb = x + (size_t)b * (DIM * PLANE);
    float* ob = out + (size_t)b * (DIM * PLANE) + (size_t)hg * DIM + wq;

    // Double-buffered 4-row x 4-float register tiles (w-edges via shuffle at use).
    float rA[4][4], rB[4][4];
    float accA[2][4], accB[2][4];     // accA -> out(p-1), accB -> out(p)
#pragma unroll
    for (int r = 0; r < 2; ++r)
#pragma unroll
        for (int j = 0; j < 4; ++j) { accA[r][j] = 0.f; accB[r][j] = 0.f; }

#define LOAD(R, P)                                                            \
    {                                                                         \
        const float* xp = xb + (size_t)(((P) & (DIM - 1)) * PLANE);           \
        _Pragma("unroll") for (int rr = 0; rr < 4; ++rr) {                    \
            const vfloat4 a = *(const vfloat4*)(xp + ro[rr]);                 \
            R[rr][0] = a.x; R[rr][1] = a.y; R[rr][2] = a.z; R[rr][3] = a.w;   \
        }                                                                     \
    }

    // Plane p contributes: K2 -> out(p-1), K1 -> out(p), K0 -> out(p+1).
#define STEP(RC, RN, I, DOLOAD)                                               \
    {                                                                         \
        const int p = d0 - 1 + (I);                                           \
        if (DOLOAD) LOAD(RN, p + 1);                                          \
        float e[4][6];                                                        \
        _Pragma("unroll") for (int rr = 0; rr < 4; ++rr) {                    \
            e[rr][0] = __shfl(RC[rr][3], lleft);   /* x[wq-1] */              \
            e[rr][1] = RC[rr][0]; e[rr][2] = RC[rr][1];                       \
            e[rr][3] = RC[rr][2]; e[rr][4] = RC[rr][3];                       \
            e[rr][5] = __shfl(RC[rr][0], lright);  /* x[wq+4] */              \
        }                                                                     \
        float c0[2][4];                                                       \
        _Pragma("unroll") for (int r = 0; r < 2; ++r)                         \
        _Pragma("unroll") for (int j = 0; j < 4; ++j) c0[r][j] = 0.f;         \
        _Pragma("unroll") for (int ch = 0; ch < 3; ++ch)                      \
        _Pragma("unroll") for (int cw = 0; cw < 3; ++cw) {                    \
            const float k0 = K0[ch * 3 + cw];                                 \
            const float k1 = K1[ch * 3 + cw];                                 \
            const float k2 = K2[ch * 3 + cw];                                 \
            _Pragma("unroll") for (int r = 0; r < 2; ++r)                     \
            _Pragma("unroll") for (int j = 0; j < 4; ++j) {                   \
                const float xv = e[r + ch][j + cw];                           \
                accA[r][j] = fmaf(k2, xv, accA[r][j]);                        \
                accB[r][j] = fmaf(k1, xv, accB[r][j]);                        \
                c0[r][j]   = fmaf(k0, xv, c0[r][j]);                          \
            }                                                                 \
        }                                                                     \
        if ((I) >= 2) {                                                       \
            float* op = ob + (size_t)(p - 1) * PLANE;                         \
            _Pragma("unroll") for (int r = 0; r < 2; ++r) {                   \
                vfloat4 v;                                                    \
                v.x = accA[r][0]; v.y = accA[r][1];                           \
                v.z = accA[r][2]; v.w = accA[r][3];                           \
                *(vfloat4*)(op + r * DIM) = v;   /* regular store: L2/L3-cached */ \
            }                                                                 \
        }                                                                     \
        _Pragma("unroll") for (int r = 0; r < 2; ++r)                        \
        _Pragma("unroll") for (int j = 0; j < 4; ++j)                         \
            { accA[r][j] = accB[r][j]; accB[r][j] = c0[r][j]; }               \
    }

    LOAD(rA, d0 - 1);

#pragma unroll 1
    for (int i = 0; i < 8; i += 2) {
        STEP(rA, rB, i, true);
        STEP(rB, rA, i + 1, true);
    }
    STEP(rA, rB, 8, true);
    STEP(rB, rA, 9, false);
#undef STEP
#undef LOAD
}

extern "C" void kernel_launch(void* const* d_in, const int* in_sizes, int n_in,
                              void* d_out, int out_size, void* d_ws, size_t ws_size,
                              hipStream_t stream) {
    const float* x    = (const float*)d_in[0];
    const float* kern = (const float*)d_in[1];
    float*       out  = (float*)d_out;
    // 8 batches x 8 h-tiles(16 rows) x 16 d-chunks(8) = 1024 blocks, 4 blocks/CU
    conv3d_circ_st<<<dim3(1024), dim3(256), 0, stream>>>(x, kern, out);
}

// Round 14
// 27.103 us; speedup vs baseline: 1.0414x; 1.0414x over previous
//
#include <hip/hip_runtime.h>

#define DIM   128
#define PLANE (DIM*DIM)
#define TD    16

typedef float vfloat4 __attribute__((ext_vector_type(4)));

__global__ __launch_bounds__(256, 4) void conv3d_circ_td16(
    const float* __restrict__ x, const float* __restrict__ kern,
    float* __restrict__ out)
{
    const int tid = threadIdx.x;
    const int bid = blockIdx.x;
    const int b  = bid >> 6;          // 8 batches (8 ht x 8 dt = 64 blocks/batch)
    const int ht = (bid >> 3) & 7;    // 8 h-tiles of 16 rows
    const int dt = bid & 7;           // 8 d-chunks of 16 planes
    const int h0 = ht * 16;
    const int d0 = dt * TD;

    const int wq   = (tid & 31) * 4;        // 4 outputs along w; 32 lanes = full W
    const int hg   = h0 + (tid >> 5) * 2;   // this thread's 2 h rows: hg, hg+1
    const int lane = tid & 63;
    const int lleft  = (lane & 32) | ((lane - 1) & 31);  // wrap within 32-lane w-ring
    const int lright = (lane & 32) | ((lane + 1) & 31);

    // 4 tap rows: hg-1, hg, hg+1, hg+2 (wrapped)
    const int ro[4] = {((hg - 1) & (DIM - 1)) * DIM + wq,
                       hg * DIM + wq,
                       ((hg + 1) & (DIM - 1)) * DIM + wq,
                       ((hg + 2) & (DIM - 1)) * DIM + wq};

    float K0[9], K1[9], K2[9];        // uniform -> scalar loads -> SGPRs
#pragma unroll
    for (int i = 0; i < 9; ++i) { K0[i] = kern[i]; K1[i] = kern[9 + i]; K2[i] = kern[18 + i]; }

    const float* xb = x + (size_t)b * (DIM * PLANE);
    float* ob = out + (size_t)b * (DIM * PLANE) + (size_t)hg * DIM + wq;

    // Double-buffered 4-row x 4-float register tiles (w-edges via shuffle at use).
    float rA[4][4], rB[4][4];
    float accA[2][4], accB[2][4];     // accA -> out(p-1), accB -> out(p)
#pragma unroll
    for (int r = 0; r < 2; ++r)
#pragma unroll
        for (int j = 0; j < 4; ++j) { accA[r][j] = 0.f; accB[r][j] = 0.f; }

#define LOAD(R, P)                                                            \
    {                                                                         \
        const float* xp = xb + (size_t)(((P) & (DIM - 1)) * PLANE);           \
        _Pragma("unroll") for (int rr = 0; rr < 4; ++rr) {                    \
            const vfloat4 a = *(const vfloat4*)(xp + ro[rr]);                 \
            R[rr][0] = a.x; R[rr][1] = a.y; R[rr][2] = a.z; R[rr][3] = a.w;   \
        }                                                                     \
    }

    // Plane p contributes: K2 -> out(p-1), K1 -> out(p), K0 -> out(p+1).
#define STEP(RC, RN, I, DOLOAD)                                               \
    {                                                                         \
        const int p = d0 - 1 + (I);                                           \
        if (DOLOAD) LOAD(RN, p + 1);                                          \
        float e[4][6];                                                        \
        _Pragma("unroll") for (int rr = 0; rr < 4; ++rr) {                    \
            e[rr][0] = __shfl(RC[rr][3], lleft);   /* x[wq-1] */              \
            e[rr][1] = RC[rr][0]; e[rr][2] = RC[rr][1];                       \
            e[rr][3] = RC[rr][2]; e[rr][4] = RC[rr][3];                       \
            e[rr][5] = __shfl(RC[rr][0], lright);  /* x[wq+4] */              \
        }                                                                     \
        float c0[2][4];                                                       \
        _Pragma("unroll") for (int r = 0; r < 2; ++r)                         \
        _Pragma("unroll") for (int j = 0; j < 4; ++j) c0[r][j] = 0.f;         \
        _Pragma("unroll") for (int ch = 0; ch < 3; ++ch)                      \
        _Pragma("unroll") for (int cw = 0; cw < 3; ++cw) {                    \
            const float k0 = K0[ch * 3 + cw];                                 \
            const float k1 = K1[ch * 3 + cw];                                 \
            const float k2 = K2[ch * 3 + cw];                                 \
            _Pragma("unroll") for (int r = 0; r < 2; ++r)                     \
            _Pragma("unroll") for (int j = 0; j < 4; ++j) {                   \
                const float xv = e[r + ch][j + cw];                           \
                accA[r][j] = fmaf(k2, xv, accA[r][j]);                        \
                accB[r][j] = fmaf(k1, xv, accB[r][j]);                        \
                c0[r][j]   = fmaf(k0, xv, c0[r][j]);                          \
            }                                                                 \
        }                                                                     \
        if ((I) >= 2) {                                                       \
            float* op = ob + (size_t)(p - 1) * PLANE;                         \
            _Pragma("unroll") for (int r = 0; r < 2; ++r) {                   \
                vfloat4 v;                                                    \
                v.x = accA[r][0]; v.y = accA[r][1];                           \
                v.z = accA[r][2]; v.w = accA[r][3];                           \
                __builtin_nontemporal_store(v, (vfloat4*)(op + r * DIM));     \
            }                                                                 \
        }                                                                     \
        _Pragma("unroll") for (int r = 0; r < 2; ++r)                        \
        _Pragma("unroll") for (int j = 0; j < 4; ++j)                         \
            { accA[r][j] = accB[r][j]; accB[r][j] = c0[r][j]; }               \
    }

    LOAD(rA, d0 - 1);

    // TD=16: 18 steps (planes d0-1 .. d0+16), stores at steps 2..17.
#pragma unroll 1
    for (int i = 0; i < 16; i += 2) {
        STEP(rA, rB, i, true);
        STEP(rB, rA, i + 1, true);
    }
    STEP(rA, rB, 16, true);
    STEP(rB, rA, 17, false);
#undef STEP
#undef LOAD
}

extern "C" void kernel_launch(void* const* d_in, const int* in_sizes, int n_in,
                              void* d_out, int out_size, void* d_ws, size_t ws_size,
                              hipStream_t stream) {
    const float* x    = (const float*)d_in[0];
    const float* kern = (const float*)d_in[1];
    float*       out  = (float*)d_out;
    // 8 batches x 8 h-tiles(16 rows) x 8 d-chunks(16) = 512 blocks, 2 blocks/CU
    conv3d_circ_td16<<<dim3(512), dim3(256), 0, stream>>>(x, kern, out);
}